// Round 13
// baseline (1127.429 us; speedup 1.0000x reference)
//
#include <hip/hip_runtime.h>

typedef unsigned short u16;
typedef _Float16 f16;
typedef __attribute__((ext_vector_type(8))) f16 f16x8;
typedef __attribute__((ext_vector_type(4))) float f32x4;
typedef __attribute__((ext_vector_type(4))) u16 u16x4;
typedef __attribute__((ext_vector_type(8))) u16 u16x8;

__device__ __forceinline__ u16 f2h(float x){
  f16 h = (f16)x;
  return __builtin_bit_cast(u16, h);
}
__device__ __forceinline__ float h2f(u16 v){
  return (float)__builtin_bit_cast(f16, v);
}

__device__ __forceinline__ void stage16(const void* g, void* l){
  __builtin_amdgcn_global_load_lds(
      (const __attribute__((address_space(1))) unsigned*)g,
      (__attribute__((address_space(3))) unsigned*)l, 16, 0, 0);
}

// ---------------- converts ----------------
__global__ __launch_bounds__(256) void convert_x3(
    const float* __restrict__ in0, const float* __restrict__ in1, const float* __restrict__ in2,
    u16* __restrict__ o0, u16* __restrict__ o1, u16* __restrict__ o2){
  const int b = blockIdx.x >> 12;
  const int i = (blockIdx.x & 4095) * 256 + threadIdx.x;
  const float* in = (b == 0) ? in0 : (b == 1) ? in1 : in2;
  u16* out = (b == 0) ? o0 : (b == 1) ? o1 : o2;
  f32x4 v = ((const f32x4*)in)[i];
  u16x4 h;
  #pragma unroll
  for (int j = 0; j < 4; j++) h[j] = f2h(v[j]);
  ((u16x4*)out)[i] = h;
}

__global__ __launch_bounds__(256) void transpose_w4(
    const float* __restrict__ W0, const float* __restrict__ W1,
    const float* __restrict__ W2, const float* __restrict__ W3,
    u16* __restrict__ t0, u16* __restrict__ t1, u16* __restrict__ t2, u16* __restrict__ t3){
  __shared__ float tile[64][68];
  const int z = blockIdx.z;
  const float* W = (z == 0) ? W0 : (z == 1) ? W1 : (z == 2) ? W2 : W3;
  u16* wt = (z == 0) ? t0 : (z == 1) ? t1 : (z == 2) ? t2 : t3;
  const int tid = threadIdx.x;
  const int k0 = blockIdx.y * 64, n0 = blockIdx.x * 64;
  #pragma unroll
  for (int g = 0; g < 4; g++){
    int flat4 = g * 256 + tid;
    int row = flat4 >> 4, c4 = flat4 & 15;
    f32x4 v = *(const f32x4*)&W[(size_t)(k0 + row) * 1024 + n0 + c4 * 4];
    *(f32x4*)&tile[row][c4 * 4] = v;
  }
  __syncthreads();
  const int n = tid >> 2, kc = (tid & 3) * 16;
  u16x8 o0, o1;
  #pragma unroll
  for (int j = 0; j < 8; j++){
    o0[j] = f2h(tile[kc + j][n]);
    o1[j] = f2h(tile[kc + 8 + j][n]);
  }
  u16* dst = &wt[(size_t)(n0 + n) * 1024 + k0 + kc];
  *(u16x8*)dst = o0;
  *(u16x8*)(dst + 8) = o1;
}

// ---------------- GEMM body ----------------
template<int MODE>
__device__ __forceinline__ void gemm_body(
    const u16* __restrict__ A, const u16* __restrict__ B,
    const float* __restrict__ bias,
    float* __restrict__ outF, u16* __restrict__ outH,
    int N, int K, int bx, int by)
{
  __shared__ u16 sA[128 * 32];
  __shared__ u16 sB[128 * 32];
  const int tid = threadIdx.x;
  const int wid = tid >> 6, lane = tid & 63;
  const int lm = lane & 15, lg = lane >> 4;
  const int bm = by * 128, bn = bx * 128;
  const int wrow = (wid >> 1) * 64, wcol = (wid & 1) * 64;
  const int srow = tid >> 2;
  const int skc  = (tid & 3) * 8;

  f32x4 acc[4][4] = {};

  for (int kt = 0; kt < K; kt += 32){
    {
      char* dA = (char*)sA + wid * 1024;
      char* dB = (char*)sB + wid * 1024;
      stage16(A + (size_t)(bm +      srow) * K + kt + skc, dA);
      stage16(A + (size_t)(bm + 64 + srow) * K + kt + skc, dA + 4096);
      stage16(B + (size_t)(bn +      srow) * K + kt + skc, dB);
      stage16(B + (size_t)(bn + 64 + srow) * K + kt + skc, dB + 4096);
    }
    __syncthreads();
    f16x8 af[4], bf[4];
    #pragma unroll
    for (int mf = 0; mf < 4; mf++)
      af[mf] = *(const f16x8*)&sA[(wrow + mf * 16 + lm) * 32 + lg * 8];
    #pragma unroll
    for (int nf = 0; nf < 4; nf++)
      bf[nf] = *(const f16x8*)&sB[(wcol + nf * 16 + lm) * 32 + lg * 8];
    #pragma unroll
    for (int mf = 0; mf < 4; mf++)
      #pragma unroll
      for (int nf = 0; nf < 4; nf++)
        acc[mf][nf] = __builtin_amdgcn_mfma_f32_16x16x32_f16(af[mf], bf[nf], acc[mf][nf], 0, 0, 0);
    __syncthreads();
  }

  #pragma unroll
  for (int mf = 0; mf < 4; mf++)
    #pragma unroll
    for (int nf = 0; nf < 4; nf++){
      const int n  = bn + wcol + nf * 16 + lm;
      const int mb = bm + wrow + mf * 16 + lg * 4;
      #pragma unroll
      for (int r = 0; r < 4; r++){
        const int m = mb + r;
        float v = acc[mf][nf][r] + ((MODE == 2) ? bias[m] : bias[n]);
        if constexpr (MODE == 0){
          outF[(size_t)m * N + n] = v;
        } else if constexpr (MODE == 1){
          const size_t idx = (((size_t)((m >> 11) * 16 + (n >> 6))) * 2048 + (m & 2047)) * 64 + (n & 63);
          outH[idx] = f2h(v);
        } else {
          const size_t idx = (((size_t)((n >> 11) * 16 + (m >> 6))) * 64 + (m & 63)) * 2048 + (n & 2047);
          outH[idx] = f2h(v);
        }
      }
    }
}

// q (z=0), k (z=1): MODE 1; v (z=2): MODE 2 with swapped operands/grid mapping
__global__ __launch_bounds__(256, 2) void gemm_qkv(
    const u16* __restrict__ xq, const u16* __restrict__ wqt, const float* __restrict__ bq, u16* __restrict__ qh,
    const u16* __restrict__ xk, const u16* __restrict__ wkt, const float* __restrict__ bk, u16* __restrict__ kh,
    const u16* __restrict__ wvt, const u16* __restrict__ xv, const float* __restrict__ bv, u16* __restrict__ vt){
  const int z = blockIdx.z;
  if (z == 2){
    gemm_body<2>(wvt, xv, bv, nullptr, vt, 4096, 1024, blockIdx.y, blockIdx.x);
  } else if (z == 1){
    gemm_body<1>(xk, wkt, bk, nullptr, kh, 1024, 1024, blockIdx.x, blockIdx.y);
  } else {
    gemm_body<1>(xq, wqt, bq, nullptr, qh, 1024, 1024, blockIdx.x, blockIdx.y);
  }
}

__global__ __launch_bounds__(256, 2) void gemm_fc(
    const u16* __restrict__ ctx, const u16* __restrict__ wft, const float* __restrict__ bfc, float* __restrict__ outF){
  gemm_body<0>(ctx, wft, bfc, outF, nullptr, 1024, 1024, blockIdx.x, blockIdx.y);
}

#define MFMA16(A, B, C) __builtin_amdgcn_mfma_f32_16x16x32_f16((A), (B), (C), 0, 0, 0)

// ---------------- fused attention (8-row tiles, 4 wg/CU, R11 structure) ----------------
// 8192 wgs: one (bh, 8-q-row tile) per wg; each of 4 waves owns a 512-col k-quarter.
// Single pass: 16-iter loop, 3-stage K/V register prefetch (distance 2); unnormalized
// exp -> per-wave [8][520] LDS buffer (33KB/wg -> 4 wg/CU); denominator same pass;
// PV on unnormalized P; end-of-wg burst store (8 rows x 2KB); ctx via LDS overlay.
// Lanes lm>=8 duplicate rows lm-8 (gated at P-write / ctx-store).
__global__ __launch_bounds__(256, 4) void attn_fused(
    const u16* __restrict__ qh_, const u16* __restrict__ kh_,
    const u16* __restrict__ vt_,
    float* __restrict__ attn_out, u16* __restrict__ ctx)
{
  constexpr int S = 2048;
  __shared__ __align__(16) char smem[4 * 8320];   // per-wave [8][520] u16 (1040B rows)
  __shared__ float sred[4][16];
  __shared__ float linv[16];
  const int tid = threadIdx.x, wid = tid >> 6, lane = tid & 63;
  const int lm = lane & 15, lg = lane >> 4;
  const int lr = lm & 7;                          // effective q-row (8 rows/wg)
  u16 (*pb)[520] = (u16 (*)[520])(smem + wid * 8320);
  float (*credw)[20] = (float (*)[20])(smem + wid * 8320);    // overlay after pb reads

  // bijective XCD swizzle: 8192 wgs, each XCD owns 4 consecutive bh entirely
  const int wg = blockIdx.x;
  const int xcd = wg & 7, li = wg >> 3;           // li 0..1023
  const int bh = (xcd << 2) + (li >> 8);          // 0..31
  const int q0 = (li & 255) * 8;
  const size_t base = (size_t)bh * S * 64;
  const u16* Qh = qh_ + base;
  const u16* Kh = kh_ + base;
  const u16* Vt = vt_ + base;                     // [64][S]
  float* Aout = attn_out + (size_t)bh * S * S;
  const int kbase = wid * 512;
  const int b = bh >> 4, h = bh & 15;
  const float SCL2 = 0.18033688011112042f;        // (1/8)*log2(e)

  // Q B-fragments: rows q0..q0+7, duplicated into lanes lm>=8
  const u16* qp = Qh + (size_t)(q0 + lr) * 64 + lg * 8;
  f16x8 qb0 = *(const f16x8*)(qp);
  f16x8 qb1 = *(const f16x8*)(qp + 32);

  f16x8 vs[3][4], ks4[3][4];
  #define LOADF(nt2_, s_) do {                                              \
    const int col0_ = kbase + (nt2_) * 32;                                  \
    _Pragma("unroll")                                                       \
    for (int nf_ = 0; nf_ < 4; nf_++)                                       \
      vs[s_][nf_] = *(const f16x8*)(Vt + (size_t)(nf_ * 16 + lm) * S + col0_ + lg * 8); \
    const u16* kp_ = Kh + (size_t)(col0_ + lm) * 64 + lg * 8;               \
    ks4[s_][0] = *(const f16x8*)(kp_);                                      \
    ks4[s_][1] = *(const f16x8*)(kp_ + 32);                                 \
    ks4[s_][2] = *(const f16x8*)(kp_ + 1024);                               \
    ks4[s_][3] = *(const f16x8*)(kp_ + 1024 + 32);                          \
  } while (0)

  LOADF(0, 0);
  LOADF(1, 1);

  float part = 0.0f;
  f32x4 cacc[4] = {};
  #pragma unroll
  for (int nt2 = 0; nt2 < 16; ++nt2){
    if (nt2 < 14) LOADF(nt2 + 2, (nt2 + 2) % 3);  // prefetch distance 2
    const int cs = nt2 % 3;
    f32x4 c0 = {}, c1 = {};
    c0 = MFMA16(ks4[cs][0], qb0, c0);
    c0 = MFMA16(ks4[cs][1], qb1, c0);
    c1 = MFMA16(ks4[cs][2], qb0, c1);
    c1 = MFMA16(ks4[cs][3], qb1, c1);
    u16x4 hp0, hp1;
    #pragma unroll
    for (int r = 0; r < 4; r++){
      float e = __builtin_amdgcn_exp2f(c0[r] * SCL2);
      part += e; hp0[r] = f2h(e);
    }
    #pragma unroll
    for (int r = 0; r < 4; r++){
      float e = __builtin_amdgcn_exp2f(c1[r] * SCL2);
      part += e; hp1[r] = f2h(e);
    }
    if (lm < 8){
      *(u16x4*)&pb[lr][nt2 * 32 + lg * 4] = hp0;
      *(u16x4*)&pb[lr][nt2 * 32 + 16 + lg * 4] = hp1;
    }
    f16x8 pa = *(const f16x8*)&pb[lr][nt2 * 32 + lg * 8];
    #pragma unroll
    for (int nf = 0; nf < 4; nf++)
      cacc[nf] = MFMA16(pa, vs[cs][nf], cacc[nf]);
  }
  #undef LOADF

  // ---- denominator combine (rows 8..15 are duplicates of 0..7, harmless) ----
  part += __shfl_xor(part, 16);
  part += __shfl_xor(part, 32);
  if (lane < 16) sred[wid][lm] = part;
  __syncthreads();
  if (tid < 16) linv[tid] = 1.0f / (sred[0][tid] + sred[1][tid] + sred[2][tid] + sred[3][tid]);
  __syncthreads();

  // ---- burst store: 8 rows x 2 chunks, 16B/lane dense (1KB per instruction) ----
  #pragma unroll 2
  for (int r = 0; r < 8; r++){
    const float iv = linv[r];
    float* rowp = Aout + (size_t)(q0 + r) * S + kbase;
    #pragma unroll
    for (int ch = 0; ch < 2; ch++){
      u16x4 hv = *(const u16x4*)&pb[r][ch * 256 + lane * 4];
      f32x4 av = { h2f(hv[0]) * iv, h2f(hv[1]) * iv, h2f(hv[2]) * iv, h2f(hv[3]) * iv };
      *(f32x4*)(rowp + ch * 256 + lane * 4) = av;
    }
  }

  // barrier: pb reads (u16 view) must complete before credw overlay writes (float view)
  __syncthreads();

  // ---- rescale PV partials; combine across waves via per-wave overlay ----
  // valid q rows are lg<2 (rows q0 + lg*4 + r, r<4 -> 0..7); lg>=2 are duplicates,
  // written into cred slots 8..15 which are never read back.
  float iv4[4];
  #pragma unroll
  for (int r = 0; r < 4; r++) iv4[r] = linv[(lg & 1) * 4 + r];
  #pragma unroll
  for (int nf = 0; nf < 4; nf++){
    f32x4 sc;
    #pragma unroll
    for (int r = 0; r < 4; r++) sc[r] = cacc[nf][r] * iv4[r];
    *(f32x4*)&credw[nf * 16 + lm][lg * 4] = sc;
  }
  __syncthreads();
  if (wid < 2){
    const float (*cr0)[20] = (const float (*)[20])(smem + 0 * 8320);
    const float (*cr1)[20] = (const float (*)[20])(smem + 1 * 8320);
    const float (*cr2)[20] = (const float (*)[20])(smem + 2 * 8320);
    const float (*cr3)[20] = (const float (*)[20])(smem + 3 * 8320);
    const int rd = lane, rq = wid * 4;            // q rows 0..7 across waves 0,1
    f32x4 s0 = *(const f32x4*)&cr0[rd][rq];
    f32x4 s1 = *(const f32x4*)&cr1[rd][rq];
    f32x4 s2 = *(const f32x4*)&cr2[rd][rq];
    f32x4 s3 = *(const f32x4*)&cr3[rd][rq];
    #pragma unroll
    for (int j = 0; j < 4; j++){
      float v = s0[j] + s1[j] + s2[j] + s3[j];
      ctx[(size_t)(b * 2048 + q0 + rq + j) * 1024 + h * 64 + rd] = f2h(v);
    }
  }
}

// ---------------- host ----------------
extern "C" void kernel_launch(void* const* d_in, const int* in_sizes, int n_in,
                              void* d_out, int out_size, void* d_ws, size_t ws_size,
                              hipStream_t stream) {
  const float* Qi  = (const float*)d_in[0];
  const float* Ki  = (const float*)d_in[1];
  const float* Vi  = (const float*)d_in[2];
  const float* Wq  = (const float*)d_in[3];
  const float* bq  = (const float*)d_in[4];
  const float* Wk  = (const float*)d_in[5];
  const float* bk  = (const float*)d_in[6];
  const float* Wv  = (const float*)d_in[7];
  const float* bv  = (const float*)d_in[8];
  const float* Wfc = (const float*)d_in[9];
  const float* bfc = (const float*)d_in[10];

  char* w = (char*)d_ws;
  const size_t P  = 8388608;    // 8 MB
  const size_t PW = 2097152;    // 2 MB
  u16* xq  = (u16*)(w + 0*P);
  u16* xk  = (u16*)(w + 1*P);
  u16* xv  = (u16*)(w + 2*P);
  u16* qh  = (u16*)(w + 3*P);
  u16* kh  = (u16*)(w + 4*P);
  u16* vt  = (u16*)(w + 5*P);
  u16* ctx = (u16*)(w + 6*P);
  char* w2 = w + 7*P;
  u16* wqt = (u16*)(w2 + 0*PW);
  u16* wkt = (u16*)(w2 + 1*PW);
  u16* wvt = (u16*)(w2 + 2*PW);
  u16* wft = (u16*)(w2 + 3*PW);

  float* outp  = (float*)d_out;
  float* attnp = outp + 4194304;          // out = 2*2048*1024

  convert_x3<<<12288, 256, 0, stream>>>(Qi, Ki, Vi, xq, xk, xv);
  transpose_w4<<<dim3(16, 16, 4), 256, 0, stream>>>(Wq, Wk, Wv, Wfc, wqt, wkt, wvt, wft);

  gemm_qkv<<<dim3(8, 32, 3), 256, 0, stream>>>(xq, wqt, bq, qh,
                                               xk, wkt, bk, kh,
                                               wvt, xv, bv, vt);
  attn_fused<<<8192, 256, 0, stream>>>(qh, kh, vt, attnp, ctx);
  gemm_fc<<<dim3(8, 32), 256, 0, stream>>>(ctx, wft, bfc, outp);
}

// Round 14
// 365.992 us; speedup vs baseline: 3.0805x; 3.0805x over previous
//
#include <hip/hip_runtime.h>

typedef unsigned short u16;
typedef _Float16 f16;
typedef __attribute__((ext_vector_type(8))) f16 f16x8;
typedef __attribute__((ext_vector_type(4))) float f32x4;
typedef __attribute__((ext_vector_type(4))) u16 u16x4;
typedef __attribute__((ext_vector_type(8))) u16 u16x8;

__device__ __forceinline__ u16 f2h(float x){
  f16 h = (f16)x;
  return __builtin_bit_cast(u16, h);
}
__device__ __forceinline__ float h2f(u16 v){
  return (float)__builtin_bit_cast(f16, v);
}

__device__ __forceinline__ void stage16(const void* g, void* l){
  __builtin_amdgcn_global_load_lds(
      (const __attribute__((address_space(1))) unsigned*)g,
      (__attribute__((address_space(3))) unsigned*)l, 16, 0, 0);
}

// ---------------- converts ----------------
__global__ __launch_bounds__(256) void convert_x3(
    const float* __restrict__ in0, const float* __restrict__ in1, const float* __restrict__ in2,
    u16* __restrict__ o0, u16* __restrict__ o1, u16* __restrict__ o2){
  const int b = blockIdx.x >> 12;
  const int i = (blockIdx.x & 4095) * 256 + threadIdx.x;
  const float* in = (b == 0) ? in0 : (b == 1) ? in1 : in2;
  u16* out = (b == 0) ? o0 : (b == 1) ? o1 : o2;
  f32x4 v = ((const f32x4*)in)[i];
  u16x4 h;
  #pragma unroll
  for (int j = 0; j < 4; j++) h[j] = f2h(v[j]);
  ((u16x4*)out)[i] = h;
}

__global__ __launch_bounds__(256) void transpose_w4(
    const float* __restrict__ W0, const float* __restrict__ W1,
    const float* __restrict__ W2, const float* __restrict__ W3,
    u16* __restrict__ t0, u16* __restrict__ t1, u16* __restrict__ t2, u16* __restrict__ t3){
  __shared__ float tile[64][68];
  const int z = blockIdx.z;
  const float* W = (z == 0) ? W0 : (z == 1) ? W1 : (z == 2) ? W2 : W3;
  u16* wt = (z == 0) ? t0 : (z == 1) ? t1 : (z == 2) ? t2 : t3;
  const int tid = threadIdx.x;
  const int k0 = blockIdx.y * 64, n0 = blockIdx.x * 64;
  #pragma unroll
  for (int g = 0; g < 4; g++){
    int flat4 = g * 256 + tid;
    int row = flat4 >> 4, c4 = flat4 & 15;
    f32x4 v = *(const f32x4*)&W[(size_t)(k0 + row) * 1024 + n0 + c4 * 4];
    *(f32x4*)&tile[row][c4 * 4] = v;
  }
  __syncthreads();
  const int n = tid >> 2, kc = (tid & 3) * 16;
  u16x8 o0, o1;
  #pragma unroll
  for (int j = 0; j < 8; j++){
    o0[j] = f2h(tile[kc + j][n]);
    o1[j] = f2h(tile[kc + 8 + j][n]);
  }
  u16* dst = &wt[(size_t)(n0 + n) * 1024 + k0 + kc];
  *(u16x8*)dst = o0;
  *(u16x8*)(dst + 8) = o1;
}

// ---------------- GEMM body ----------------
template<int MODE>
__device__ __forceinline__ void gemm_body(
    const u16* __restrict__ A, const u16* __restrict__ B,
    const float* __restrict__ bias,
    float* __restrict__ outF, u16* __restrict__ outH,
    int N, int K, int bx, int by)
{
  __shared__ u16 sA[128 * 32];
  __shared__ u16 sB[128 * 32];
  const int tid = threadIdx.x;
  const int wid = tid >> 6, lane = tid & 63;
  const int lm = lane & 15, lg = lane >> 4;
  const int bm = by * 128, bn = bx * 128;
  const int wrow = (wid >> 1) * 64, wcol = (wid & 1) * 64;
  const int srow = tid >> 2;
  const int skc  = (tid & 3) * 8;

  f32x4 acc[4][4] = {};

  for (int kt = 0; kt < K; kt += 32){
    {
      char* dA = (char*)sA + wid * 1024;
      char* dB = (char*)sB + wid * 1024;
      stage16(A + (size_t)(bm +      srow) * K + kt + skc, dA);
      stage16(A + (size_t)(bm + 64 + srow) * K + kt + skc, dA + 4096);
      stage16(B + (size_t)(bn +      srow) * K + kt + skc, dB);
      stage16(B + (size_t)(bn + 64 + srow) * K + kt + skc, dB + 4096);
    }
    __syncthreads();
    f16x8 af[4], bf[4];
    #pragma unroll
    for (int mf = 0; mf < 4; mf++)
      af[mf] = *(const f16x8*)&sA[(wrow + mf * 16 + lm) * 32 + lg * 8];
    #pragma unroll
    for (int nf = 0; nf < 4; nf++)
      bf[nf] = *(const f16x8*)&sB[(wcol + nf * 16 + lm) * 32 + lg * 8];
    #pragma unroll
    for (int mf = 0; mf < 4; mf++)
      #pragma unroll
      for (int nf = 0; nf < 4; nf++)
        acc[mf][nf] = __builtin_amdgcn_mfma_f32_16x16x32_f16(af[mf], bf[nf], acc[mf][nf], 0, 0, 0);
    __syncthreads();
  }

  #pragma unroll
  for (int mf = 0; mf < 4; mf++)
    #pragma unroll
    for (int nf = 0; nf < 4; nf++){
      const int n  = bn + wcol + nf * 16 + lm;
      const int mb = bm + wrow + mf * 16 + lg * 4;
      #pragma unroll
      for (int r = 0; r < 4; r++){
        const int m = mb + r;
        float v = acc[mf][nf][r] + ((MODE == 2) ? bias[m] : bias[n]);
        if constexpr (MODE == 0){
          outF[(size_t)m * N + n] = v;
        } else if constexpr (MODE == 1){
          const size_t idx = (((size_t)((m >> 11) * 16 + (n >> 6))) * 2048 + (m & 2047)) * 64 + (n & 63);
          outH[idx] = f2h(v);
        } else {
          const size_t idx = (((size_t)((n >> 11) * 16 + (m >> 6))) * 64 + (m & 63)) * 2048 + (n & 2047);
          outH[idx] = f2h(v);
        }
      }
    }
}

// q (z=0), k (z=1): MODE 1; v (z=2): MODE 2 with swapped operands/grid mapping
__global__ __launch_bounds__(256, 2) void gemm_qkv(
    const u16* __restrict__ xq, const u16* __restrict__ wqt, const float* __restrict__ bq, u16* __restrict__ qh,
    const u16* __restrict__ xk, const u16* __restrict__ wkt, const float* __restrict__ bk, u16* __restrict__ kh,
    const u16* __restrict__ wvt, const u16* __restrict__ xv, const float* __restrict__ bv, u16* __restrict__ vt){
  const int z = blockIdx.z;
  if (z == 2){
    gemm_body<2>(wvt, xv, bv, nullptr, vt, 4096, 1024, blockIdx.y, blockIdx.x);
  } else if (z == 1){
    gemm_body<1>(xk, wkt, bk, nullptr, kh, 1024, 1024, blockIdx.x, blockIdx.y);
  } else {
    gemm_body<1>(xq, wqt, bq, nullptr, qh, 1024, 1024, blockIdx.x, blockIdx.y);
  }
}

__global__ __launch_bounds__(256, 2) void gemm_fc(
    const u16* __restrict__ ctx, const u16* __restrict__ wft, const float* __restrict__ bfc, float* __restrict__ outF){
  gemm_body<0>(ctx, wft, bfc, outF, nullptr, 1024, 1024, blockIdx.x, blockIdx.y);
}

#define MFMA16(A, B, C) __builtin_amdgcn_mfma_f32_16x16x32_f16((A), (B), (C), 0, 0, 0)

// ---------------- fused attention (one task/wg + register prefetch + burst store) ----------
// 4096 wgs: one (bh, 16-q-row tile) per wg; each of 4 waves owns a 512-col k-quarter.
// 16-iter compute loop, 3-stage register prefetch of K/V (prefetch distance 2);
// unnormalized exp -> per-wave LDS buffer, denominator same pass; PV on unnormalized P;
// dense burst store (1KB/instruction, 128KB contiguous per wg); ctx combined via LDS.
// [R14: byte-identical restore of the R11 kernel — best measured config, 367us total.]
__global__ __launch_bounds__(256, 2) void attn_fused(
    const u16* __restrict__ qh_, const u16* __restrict__ kh_,
    const u16* __restrict__ vt_,
    float* __restrict__ attn_out, u16* __restrict__ ctx)
{
  constexpr int S = 2048;
  __shared__ __align__(16) char smem[4 * 16640];   // per-wave [16][520] u16 (1040B rows)
  __shared__ float sred[4][16];
  __shared__ float linv[16];
  const int tid = threadIdx.x, wid = tid >> 6, lane = tid & 63;
  const int lm = lane & 15, lg = lane >> 4;
  u16 (*pb)[520] = (u16 (*)[520])(smem + wid * 16640);
  float (*credw)[20] = (float (*)[20])(smem + wid * 16640);   // overlay after pb reads

  // bijective XCD swizzle: 4096 wgs, each XCD owns 4 consecutive bh entirely
  const int wg = blockIdx.x;
  const int xcd = wg & 7, li = wg >> 3;           // li 0..511
  const int bh = (xcd << 2) + (li >> 7);          // 0..31
  const int q0 = (li & 127) * 16;
  const size_t base = (size_t)bh * S * 64;
  const u16* Qh = qh_ + base;
  const u16* Kh = kh_ + base;
  const u16* Vt = vt_ + base;                     // [64][S]
  float* Aout = attn_out + (size_t)bh * S * S;
  const int kbase = wid * 512;
  const int b = bh >> 4, h = bh & 15;
  const float SCL2 = 0.18033688011112042f;        // (1/8)*log2(e)

  // Q B-fragments (16 q rows, shared by all waves)
  const u16* qp = Qh + (size_t)(q0 + lm) * 64 + lg * 8;
  f16x8 qb0 = *(const f16x8*)(qp);
  f16x8 qb1 = *(const f16x8*)(qp + 32);

  f16x8 vs[3][4], ks4[3][4];
  #define LOADF(nt2_, s_) do {                                              \
    const int col0_ = kbase + (nt2_) * 32;                                  \
    _Pragma("unroll")                                                       \
    for (int nf_ = 0; nf_ < 4; nf_++)                                       \
      vs[s_][nf_] = *(const f16x8*)(Vt + (size_t)(nf_ * 16 + lm) * S + col0_ + lg * 8); \
    const u16* kp_ = Kh + (size_t)(col0_ + lm) * 64 + lg * 8;               \
    ks4[s_][0] = *(const f16x8*)(kp_);                                      \
    ks4[s_][1] = *(const f16x8*)(kp_ + 32);                                 \
    ks4[s_][2] = *(const f16x8*)(kp_ + 1024);                               \
    ks4[s_][3] = *(const f16x8*)(kp_ + 1024 + 32);                          \
  } while (0)

  LOADF(0, 0);
  LOADF(1, 1);

  float part = 0.0f;
  f32x4 cacc[4] = {};
  #pragma unroll
  for (int nt2 = 0; nt2 < 16; ++nt2){
    if (nt2 < 14) LOADF(nt2 + 2, (nt2 + 2) % 3);  // prefetch distance 2
    const int cs = nt2 % 3;
    f32x4 c0 = {}, c1 = {};
    c0 = MFMA16(ks4[cs][0], qb0, c0);
    c0 = MFMA16(ks4[cs][1], qb1, c0);
    c1 = MFMA16(ks4[cs][2], qb0, c1);
    c1 = MFMA16(ks4[cs][3], qb1, c1);
    u16x4 hp0, hp1;
    #pragma unroll
    for (int r = 0; r < 4; r++){
      float e = __builtin_amdgcn_exp2f(c0[r] * SCL2);
      part += e; hp0[r] = f2h(e);
    }
    #pragma unroll
    for (int r = 0; r < 4; r++){
      float e = __builtin_amdgcn_exp2f(c1[r] * SCL2);
      part += e; hp1[r] = f2h(e);
    }
    *(u16x4*)&pb[lm][nt2 * 32 + lg * 4] = hp0;
    *(u16x4*)&pb[lm][nt2 * 32 + 16 + lg * 4] = hp1;
    f16x8 pa = *(const f16x8*)&pb[lm][nt2 * 32 + lg * 8];
    #pragma unroll
    for (int nf = 0; nf < 4; nf++)
      cacc[nf] = MFMA16(pa, vs[cs][nf], cacc[nf]);
  }
  #undef LOADF

  // ---- denominator combine ----
  part += __shfl_xor(part, 16);
  part += __shfl_xor(part, 32);
  if (lane < 16) sred[wid][lm] = part;
  __syncthreads();
  if (tid < 16) linv[tid] = 1.0f / (sred[0][tid] + sred[1][tid] + sred[2][tid] + sred[3][tid]);
  __syncthreads();

  // ---- burst store: 16 rows x 2 chunks, 16B/lane dense (1KB per instruction) ----
  #pragma unroll 2
  for (int r = 0; r < 16; r++){
    const float iv = linv[r];
    float* rowp = Aout + (size_t)(q0 + r) * S + kbase;
    #pragma unroll
    for (int ch = 0; ch < 2; ch++){
      u16x4 hv = *(const u16x4*)&pb[r][ch * 256 + lane * 4];
      f32x4 av = { h2f(hv[0]) * iv, h2f(hv[1]) * iv, h2f(hv[2]) * iv, h2f(hv[3]) * iv };
      *(f32x4*)(rowp + ch * 256 + lane * 4) = av;
    }
  }

  // barrier: pb reads (u16 view) must complete before credw overlay writes (float view)
  __syncthreads();

  // ---- rescale PV partials; combine across waves via per-wave overlay ----
  float iv4[4];
  #pragma unroll
  for (int r = 0; r < 4; r++) iv4[r] = linv[lg * 4 + r];
  #pragma unroll
  for (int nf = 0; nf < 4; nf++){
    f32x4 sc;
    #pragma unroll
    for (int r = 0; r < 4; r++) sc[r] = cacc[nf][r] * iv4[r];
    *(f32x4*)&credw[nf * 16 + lm][lg * 4] = sc;
  }
  __syncthreads();
  {
    const float (*cr0)[20] = (const float (*)[20])(smem + 0 * 16640);
    const float (*cr1)[20] = (const float (*)[20])(smem + 1 * 16640);
    const float (*cr2)[20] = (const float (*)[20])(smem + 2 * 16640);
    const float (*cr3)[20] = (const float (*)[20])(smem + 3 * 16640);
    const int rd = lane, rq = wid * 4;
    f32x4 s0 = *(const f32x4*)&cr0[rd][rq];
    f32x4 s1 = *(const f32x4*)&cr1[rd][rq];
    f32x4 s2 = *(const f32x4*)&cr2[rd][rq];
    f32x4 s3 = *(const f32x4*)&cr3[rd][rq];
    #pragma unroll
    for (int j = 0; j < 4; j++){
      float v = s0[j] + s1[j] + s2[j] + s3[j];
      ctx[(size_t)(b * 2048 + q0 + rq + j) * 1024 + h * 64 + rd] = f2h(v);
    }
  }
}

// ---------------- host ----------------
extern "C" void kernel_launch(void* const* d_in, const int* in_sizes, int n_in,
                              void* d_out, int out_size, void* d_ws, size_t ws_size,
                              hipStream_t stream) {
  const float* Qi  = (const float*)d_in[0];
  const float* Ki  = (const float*)d_in[1];
  const float* Vi  = (const float*)d_in[2];
  const float* Wq  = (const float*)d_in[3];
  const float* bq  = (const float*)d_in[4];
  const float* Wk  = (const float*)d_in[5];
  const float* bk  = (const float*)d_in[6];
  const float* Wv  = (const float*)d_in[7];
  const float* bv  = (const float*)d_in[8];
  const float* Wfc = (const float*)d_in[9];
  const float* bfc = (const float*)d_in[10];

  char* w = (char*)d_ws;
  const size_t P  = 8388608;    // 8 MB
  const size_t PW = 2097152;    // 2 MB
  u16* xq  = (u16*)(w + 0*P);
  u16* xk  = (u16*)(w + 1*P);
  u16* xv  = (u16*)(w + 2*P);
  u16* qh  = (u16*)(w + 3*P);
  u16* kh  = (u16*)(w + 4*P);
  u16* vt  = (u16*)(w + 5*P);
  u16* ctx = (u16*)(w + 6*P);
  char* w2 = w + 7*P;
  u16* wqt = (u16*)(w2 + 0*PW);
  u16* wkt = (u16*)(w2 + 1*PW);
  u16* wvt = (u16*)(w2 + 2*PW);
  u16* wft = (u16*)(w2 + 3*PW);

  float* outp  = (float*)d_out;
  float* attnp = outp + 4194304;          // out = 2*2048*1024

  convert_x3<<<12288, 256, 0, stream>>>(Qi, Ki, Vi, xq, xk, xv);
  transpose_w4<<<dim3(16, 16, 4), 256, 0, stream>>>(Wq, Wk, Wv, Wfc, wqt, wkt, wvt, wft);

  gemm_qkv<<<dim3(8, 32, 3), 256, 0, stream>>>(xq, wqt, bq, qh,
                                               xk, wkt, bk, kh,
                                               wvt, xv, bv, vt);
  attn_fused<<<4096, 256, 0, stream>>>(qh, kh, vt, attnp, ctx);
  gemm_fc<<<dim3(8, 32), 256, 0, stream>>>(ctx, wft, bfc, outp);
}